// Round 1
// baseline (595.622 us; speedup 1.0000x reference)
//
#include <hip/hip_runtime.h>

#define NN 100000
#define NE 600000
#define D  128

// ---------------- CSR build ----------------

__global__ void zero_kernel(int* __restrict__ p, int n) {
    int i = blockIdx.x * blockDim.x + threadIdx.x;
    if (i < n) p[i] = 0;
}

__global__ void hist_kernel(const int* __restrict__ dst, int* __restrict__ counts, int e) {
    int i = blockIdx.x * blockDim.x + threadIdx.x;
    if (i < e) atomicAdd(&counts[dst[i]], 1);
}

__global__ __launch_bounds__(1024) void scan_kernel(const int* __restrict__ counts,
                                                    int* __restrict__ offsets,
                                                    int* __restrict__ cursor, int n) {
    __shared__ int sums[1024];
    const int T = 1024;
    int t = threadIdx.x;
    int chunk = (n + T - 1) / T;
    int begin = t * chunk;
    int end = begin + chunk; if (end > n) end = n;
    int s = 0;
    for (int i = begin; i < end && i >= 0; ++i) s += counts[i];
    sums[t] = s;
    __syncthreads();
    // Hillis-Steele inclusive scan over 1024 partial sums
    for (int off = 1; off < T; off <<= 1) {
        int v = (t >= off) ? sums[t - off] : 0;
        __syncthreads();
        sums[t] += v;
        __syncthreads();
    }
    int run = (t == 0) ? 0 : sums[t - 1];   // exclusive prefix of this chunk
    for (int i = begin; i < end && i >= 0; ++i) {
        offsets[i] = run;
        cursor[i]  = run;
        run += counts[i];
    }
    if (t == T - 1) offsets[n] = run;       // total edge count
}

__global__ void scatter_kernel(const int* __restrict__ src, const int* __restrict__ dst,
                               int* __restrict__ cursor, int* __restrict__ sorted_src, int e) {
    int i = blockIdx.x * blockDim.x + threadIdx.x;
    if (i < e) {
        int d = dst[i];
        int pos = atomicAdd(&cursor[d], 1);
        sorted_src[pos] = src[i];
    }
}

// ---------------- segment product ----------------
// one block (128 threads) per node; thread t owns feature dim t.
__global__ __launch_bounds__(128) void aggregate_kernel(const float* __restrict__ x,
                                                        const int* __restrict__ offsets,
                                                        const int* __restrict__ sorted_src,
                                                        float* __restrict__ aggr, int n) {
    int node = blockIdx.x;
    if (node >= n) return;
    int d = threadIdx.x;
    int b = offsets[node], e2 = offsets[node + 1];
    float prod = 1.0f;
    for (int i = b; i < e2; ++i) {
        int s = sorted_src[i];
        prod *= x[(size_t)s * D + d];      // 128 lanes read one contiguous row: coalesced
    }
    aggr[(size_t)node * D + d] = prod;
}

// ---------------- fused dual-GEMM + multiply ----------------
// out[n][o] = (x[n]·W1[o] + b1[o]) * (aggr[n]·W2[o] + b2[o])
// Persistent blocks; W1^T, W2^T staged once in LDS (128 KB); 8 nodes per iter.
// Thread layout: slot = tid>>5 (node 0..7), o4 = (tid&31)*4 (4 contiguous outputs).
__global__ __launch_bounds__(256) void fused_kernel(const float* __restrict__ x,
                                                    const float* __restrict__ aggr,
                                                    const float* __restrict__ W1,
                                                    const float* __restrict__ b1,
                                                    const float* __restrict__ W2,
                                                    const float* __restrict__ b2,
                                                    float* __restrict__ out, int n) {
    __shared__ float sW1[D * D];   // transposed: sW1[k*D + o]
    __shared__ float sW2[D * D];
    __shared__ float sx[8][D];
    __shared__ float sa[8][D];

    for (int i = threadIdx.x; i < D * D; i += 256) {
        int o = i >> 7, k = i & (D - 1);         // W row-major [o][k], coalesced global read
        sW1[k * D + o] = W1[i];
        sW2[k * D + o] = W2[i];
    }
    const int o4   = (threadIdx.x & 31) << 2;
    const int slot = threadIdx.x >> 5;
    const float4 bb1 = *(const float4*)&b1[o4];
    const float4 bb2 = *(const float4*)&b2[o4];
    __syncthreads();

    for (int base = blockIdx.x * 8; base < n; base += gridDim.x * 8) {
        // stage 8 x-rows + 8 aggr-rows (2 KB each array): 256 threads × 1 float4 each
        {
            int t = threadIdx.x;
            int r = t >> 5;                 // row 0..7
            int c = (t & 31) << 2;          // col (float4)
            int nn = base + r;
            if (nn < n) {
                *(float4*)&sx[r][c] = *(const float4*)&x[(size_t)nn * D + c];
                *(float4*)&sa[r][c] = *(const float4*)&aggr[(size_t)nn * D + c];
            }
        }
        __syncthreads();
        int node = base + slot;
        if (node < n) {
            float a1x = 0.f, a1y = 0.f, a1z = 0.f, a1w = 0.f;
            float a2x = 0.f, a2y = 0.f, a2z = 0.f, a2w = 0.f;
#pragma unroll 4
            for (int k = 0; k < D; ++k) {
                float xv = sx[slot][k];     // broadcast (2 distinct addrs/wave: free)
                float av = sa[slot][k];
                float4 w1 = *(const float4*)&sW1[k * D + o4];   // ds_read_b128
                float4 w2 = *(const float4*)&sW2[k * D + o4];
                a1x += xv * w1.x; a1y += xv * w1.y; a1z += xv * w1.z; a1w += xv * w1.w;
                a2x += av * w2.x; a2y += av * w2.y; a2z += av * w2.z; a2w += av * w2.w;
            }
            float4 r;
            r.x = (a1x + bb1.x) * (a2x + bb2.x);
            r.y = (a1y + bb1.y) * (a2y + bb2.y);
            r.z = (a1z + bb1.z) * (a2z + bb2.z);
            r.w = (a1w + bb1.w) * (a2w + bb2.w);
            *(float4*)&out[(size_t)node * D + o4] = r;
        }
        __syncthreads();
    }
}

// ---------------- launch ----------------

extern "C" void kernel_launch(void* const* d_in, const int* in_sizes, int n_in,
                              void* d_out, int out_size, void* d_ws, size_t ws_size,
                              hipStream_t stream) {
    const float* x  = (const float*)d_in[0];
    const int*   ei = (const int*)d_in[1];
    const float* W1 = (const float*)d_in[2];
    const float* b1 = (const float*)d_in[3];
    const float* W2 = (const float*)d_in[4];
    const float* b2 = (const float*)d_in[5];
    float* out = (float*)d_out;

    const int n = NN, e = NE;
    const int* src = ei;          // edge_index[0]
    const int* dst = ei + e;      // edge_index[1]

    char* ws = (char*)d_ws;
    float* aggr = (float*)ws;               ws += (size_t)n * D * sizeof(float);
    int* counts = (int*)ws;                 ws += (size_t)n * sizeof(int);
    int* offsets = (int*)ws;                ws += (size_t)(n + 1) * sizeof(int);
    ws += 256 - ((uintptr_t)ws & 255);      // realign
    int* cursor = (int*)ws;                 ws += (size_t)n * sizeof(int);
    int* sorted_src = (int*)ws;             /* e ints */

    zero_kernel<<<(n + 255) / 256, 256, 0, stream>>>(counts, n);
    hist_kernel<<<(e + 255) / 256, 256, 0, stream>>>(dst, counts, e);
    scan_kernel<<<1, 1024, 0, stream>>>(counts, offsets, cursor, n);
    scatter_kernel<<<(e + 255) / 256, 256, 0, stream>>>(src, dst, cursor, sorted_src, e);
    aggregate_kernel<<<n, 128, 0, stream>>>(x, offsets, sorted_src, aggr, n);
    fused_kernel<<<256, 256, 0, stream>>>(x, aggr, W1, b1, W2, b2, out, n);
}

// Round 2
// 342.454 us; speedup vs baseline: 1.7393x; 1.7393x over previous
//
#include <hip/hip_runtime.h>

#define NN 100000
#define NE 600000
#define D  128
#define CHUNK 1024
#define NCH ((NN + CHUNK - 1) / CHUNK)   // 98

// ---------------- CSR build ----------------

__global__ void zero_kernel(int* __restrict__ p, int n) {
    int i = blockIdx.x * blockDim.x + threadIdx.x;
    if (i < n) p[i] = 0;
}

__global__ void hist_kernel(const int* __restrict__ dst, int* __restrict__ counts, int e) {
    int i = blockIdx.x * blockDim.x + threadIdx.x;
    if (i < e) atomicAdd(&counts[dst[i]], 1);
}

// chunk partial sums (coalesced)
__global__ __launch_bounds__(256) void chunk_sum_kernel(const int* __restrict__ counts,
                                                        int* __restrict__ bsum, int n) {
    __shared__ int s[256];
    int c = blockIdx.x, t = threadIdx.x;
    int sum = 0;
    int end = (c + 1) * CHUNK; if (end > n) end = n;
    for (int i = c * CHUNK + t; i < end; i += 256) sum += counts[i];
    s[t] = sum; __syncthreads();
    for (int off = 128; off > 0; off >>= 1) {
        if (t < off) s[t] += s[t + off];
        __syncthreads();
    }
    if (t == 0) bsum[c] = s[0];
}

// scan the 98 chunk sums in one small block
__global__ __launch_bounds__(128) void chunk_scan_kernel(const int* __restrict__ bsum,
                                                         int* __restrict__ bpre,
                                                         int* __restrict__ offsets /* [NN+1] */) {
    __shared__ int s[128];
    int t = threadIdx.x;
    int v = (t < NCH) ? bsum[t] : 0;
    s[t] = v; __syncthreads();
    for (int off = 1; off < 128; off <<= 1) {
        int u = (t >= off) ? s[t - off] : 0;
        __syncthreads();
        s[t] += u;
        __syncthreads();
    }
    if (t < NCH) bpre[t] = s[t] - v;
    if (t == 127) offsets[NN] = s[127];
}

// per-chunk exclusive scan -> offsets & cursor (coalesced)
__global__ __launch_bounds__(CHUNK) void offsets_kernel(const int* __restrict__ counts,
                                                        const int* __restrict__ bpre,
                                                        int* __restrict__ offsets,
                                                        int* __restrict__ cursor, int n) {
    __shared__ int s[CHUNK];
    int t = threadIdx.x;
    int i = blockIdx.x * CHUNK + t;
    int v = (i < n) ? counts[i] : 0;
    s[t] = v; __syncthreads();
    for (int off = 1; off < CHUNK; off <<= 1) {
        int u = (t >= off) ? s[t - off] : 0;
        __syncthreads();
        s[t] += u;
        __syncthreads();
    }
    if (i < n) {
        int ex = s[t] - v + bpre[blockIdx.x];
        offsets[i] = ex;
        cursor[i]  = ex;
    }
}

__global__ void scatter_kernel(const int* __restrict__ src, const int* __restrict__ dst,
                               int* __restrict__ cursor, int* __restrict__ sorted_src, int e) {
    int i = blockIdx.x * blockDim.x + threadIdx.x;
    if (i < e) {
        int d = dst[i];
        int pos = atomicAdd(&cursor[d], 1);
        sorted_src[pos] = src[i];
    }
}

// ---------------- segment product ----------------
// grid-stride, 2 nodes per 256-thread block, edge loop unrolled x4 (4 rows in flight)
__global__ __launch_bounds__(256) void aggregate_kernel(const float* __restrict__ x,
                                                        const int* __restrict__ offsets,
                                                        const int* __restrict__ ssrc,
                                                        float* __restrict__ aggr, int n) {
    int d = threadIdx.x & (D - 1);
    int slot = threadIdx.x >> 7;       // 0..1
    for (int node = blockIdx.x * 2 + slot; node < n; node += gridDim.x * 2) {
        int b = offsets[node], e2 = offsets[node + 1];
        float p0 = 1.f, p1 = 1.f, p2 = 1.f, p3 = 1.f;
        int i = b;
        for (; i + 4 <= e2; i += 4) {
            int s0 = ssrc[i], s1 = ssrc[i + 1], s2 = ssrc[i + 2], s3 = ssrc[i + 3];
            p0 *= x[(size_t)s0 * D + d];
            p1 *= x[(size_t)s1 * D + d];
            p2 *= x[(size_t)s2 * D + d];
            p3 *= x[(size_t)s3 * D + d];
        }
        for (; i < e2; ++i) p0 *= x[(size_t)ssrc[i] * D + d];
        aggr[(size_t)node * D + d] = (p0 * p1) * (p2 * p3);
    }
}

// ---------------- fused dual-GEMM + multiply ----------------
// out[n][o] = (x[n].W1[o] + b1[o]) * (aggr[n].W2[o] + b2[o])
// 512 threads = 8 waves; wave w owns 8 nodes/iter (npt=8 -> W LDS traffic /8).
// Lane l computes outputs o=2l,2l+1 via rows sW[o][*] (stride 129: conflict-free
// b128 reads AND conflict-free staging writes). x/aggr rows are read with
// wave-uniform addresses -> scalar loads, L2/L3-resident. No per-iter barriers.
__global__ __launch_bounds__(512) void fused_kernel(const float* __restrict__ x,
                                                    const float* __restrict__ aggr,
                                                    const float* __restrict__ W1,
                                                    const float* __restrict__ b1,
                                                    const float* __restrict__ W2,
                                                    const float* __restrict__ b2,
                                                    float* __restrict__ out, int n) {
    __shared__ float sW1[D * (D + 1)];   // [o][k], row stride 129 floats
    __shared__ float sW2[D * (D + 1)];

    for (int i = threadIdx.x; i < D * D; i += 512) {
        int o = i >> 7, k = i & (D - 1);     // coalesced global read; conflict-free LDS write
        sW1[o * (D + 1) + k] = W1[i];
        sW2[o * (D + 1) + k] = W2[i];
    }
    const int lane = threadIdx.x & 63;
    const int wv = __builtin_amdgcn_readfirstlane((int)(threadIdx.x >> 6));  // wave id 0..7 (SGPR)
    const int o2 = lane << 1;
    const float2 bb1 = *(const float2*)&b1[o2];
    const float2 bb2 = *(const float2*)&b2[o2];
    __syncthreads();

    const float* __restrict__ w1a = &sW1[o2 * (D + 1)];
    const float* __restrict__ w1b = &sW1[(o2 + 1) * (D + 1)];
    const float* __restrict__ w2a = &sW2[o2 * (D + 1)];
    const float* __restrict__ w2b = &sW2[(o2 + 1) * (D + 1)];

    const int stride = gridDim.x * 64;
    for (int base = blockIdx.x * 64 + wv * 8; base < n; base += stride) {
        // NN is a multiple of 8, so base < n implies all 8 nodes valid.
        float2 a1[8], a2[8];
#pragma unroll
        for (int j = 0; j < 8; ++j) {
            a1[j] = make_float2(0.f, 0.f);
            a2[j] = make_float2(0.f, 0.f);
        }
        const float* __restrict__ xp = &x[(size_t)base * D];
        const float* __restrict__ ap = &aggr[(size_t)base * D];
#pragma unroll 2
        for (int kb = 0; kb < D; kb += 4) {
            const float4 u1 = *(const float4*)&w1a[kb];
            const float4 v1 = *(const float4*)&w1b[kb];
            const float4 u2 = *(const float4*)&w2a[kb];
            const float4 v2 = *(const float4*)&w2b[kb];
#pragma unroll
            for (int j = 0; j < 8; ++j) {
                const float4 xv = *(const float4*)&xp[j * D + kb];   // wave-uniform -> s_load
                const float4 av = *(const float4*)&ap[j * D + kb];
                a1[j].x += xv.x * u1.x + xv.y * u1.y + xv.z * u1.z + xv.w * u1.w;
                a1[j].y += xv.x * v1.x + xv.y * v1.y + xv.z * v1.z + xv.w * v1.w;
                a2[j].x += av.x * u2.x + av.y * u2.y + av.z * u2.z + av.w * u2.w;
                a2[j].y += av.x * v2.x + av.y * v2.y + av.z * v2.z + av.w * v2.w;
            }
        }
#pragma unroll
        for (int j = 0; j < 8; ++j) {
            float2 r;
            r.x = (a1[j].x + bb1.x) * (a2[j].x + bb2.x);
            r.y = (a1[j].y + bb1.y) * (a2[j].y + bb2.y);
            *(float2*)&out[(size_t)(base + j) * D + o2] = r;
        }
    }
}

// ---------------- launch ----------------

extern "C" void kernel_launch(void* const* d_in, const int* in_sizes, int n_in,
                              void* d_out, int out_size, void* d_ws, size_t ws_size,
                              hipStream_t stream) {
    const float* x  = (const float*)d_in[0];
    const int*   ei = (const int*)d_in[1];
    const float* W1 = (const float*)d_in[2];
    const float* b1 = (const float*)d_in[3];
    const float* W2 = (const float*)d_in[4];
    const float* b2 = (const float*)d_in[5];
    float* out = (float*)d_out;

    const int n = NN, e = NE;
    const int* src = ei;          // edge_index[0]
    const int* dst = ei + e;      // edge_index[1]

    char* ws = (char*)d_ws;
    float* aggr = (float*)ws;               ws += (size_t)n * D * sizeof(float);
    int* counts = (int*)ws;                 ws += (size_t)n * sizeof(int);
    int* offsets = (int*)ws;                ws += (size_t)(n + 1) * sizeof(int);
    ws += 256 - ((uintptr_t)ws & 255);
    int* cursor = (int*)ws;                 ws += (size_t)n * sizeof(int);
    int* sorted_src = (int*)ws;             ws += (size_t)e * sizeof(int);
    int* bsum = (int*)ws;                   ws += (size_t)NCH * sizeof(int);
    int* bpre = (int*)ws;                   /* NCH ints */

    zero_kernel<<<(n + 255) / 256, 256, 0, stream>>>(counts, n);
    hist_kernel<<<(e + 255) / 256, 256, 0, stream>>>(dst, counts, e);
    chunk_sum_kernel<<<NCH, 256, 0, stream>>>(counts, bsum, n);
    chunk_scan_kernel<<<1, 128, 0, stream>>>(bsum, bpre, offsets);
    offsets_kernel<<<NCH, CHUNK, 0, stream>>>(counts, bpre, offsets, cursor, n);
    scatter_kernel<<<(e + 255) / 256, 256, 0, stream>>>(src, dst, cursor, sorted_src, e);
    aggregate_kernel<<<2048, 256, 0, stream>>>(x, offsets, sorted_src, aggr, n);
    fused_kernel<<<256, 512, 0, stream>>>(x, aggr, W1, b1, W2, b2, out, n);
}